// Round 6
// baseline (190.449 us; speedup 1.0000x reference)
//
#include <hip/hip_runtime.h>

#define NROIS 512
#define CH    256
#define HH    128
#define WW    128
#define SCALE 0.0625f
#define GAMMA 0.1f

// Transposed copy of x: (B,C,H,W) -> (B,H,W,C). 4*128*128*256 floats = 64 MiB.
#define XT_BYTES ((size_t)4 * 128 * 128 * 256 * 4)

// ---------------------------------------------------------------------------
// Kernel 1: tiled transpose per batch: 256 (C) x 16384 (HW) -> 16384 x 256.
// float4 both phases; LDS conflicts are 2-way max (free on gfx950).
// ---------------------------------------------------------------------------
__global__ __launch_bounds__(256) void transpose_kernel(
    const float* __restrict__ x, float* __restrict__ xt)
{
    __shared__ float tile[64][65];           // [c][p], +1 pad
    const int bid = blockIdx.x;              // 256 p-tiles * 4 c-tiles * 4 batches
    const int pt  = bid & 255;
    const int ct  = (bid >> 8) & 3;
    const int b   = bid >> 10;
    const int p0  = pt * 64, c0 = ct * 64;
    const size_t boff = (size_t)b * (256 * 16384);
    const int a = threadIdx.x & 15;          // float4 slot
    const int r = threadIdx.x >> 4;          // 0..15

    #pragma unroll
    for (int i = 0; i < 4; ++i) {            // coalesced float4 reads along HW
        const int cr = r + 16 * i;
        const float4 v = *(const float4*)(x + boff + (size_t)(c0 + cr) * 16384 + p0 + 4 * a);
        tile[cr][4 * a + 0] = v.x;
        tile[cr][4 * a + 1] = v.y;
        tile[cr][4 * a + 2] = v.z;
        tile[cr][4 * a + 3] = v.w;
    }
    __syncthreads();
    #pragma unroll
    for (int i = 0; i < 4; ++i) {            // coalesced float4 writes along C
        const int pr = r + 16 * i;
        float4 v;
        v.x = tile[4 * a + 0][pr];
        v.y = tile[4 * a + 1][pr];
        v.z = tile[4 * a + 2][pr];
        v.w = tile[4 * a + 3][pr];
        *(float4*)(xt + boff + (size_t)(p0 + pr) * 256 + c0 + 4 * a) = v;
    }
}

// ---------------------------------------------------------------------------
// Kernel 2: ONE BLOCK (512 threads, 8 waves) PER ROI. Lane l owns channels
// 4l..4l+3 (one coalesced dwordx4 per tap); wave w handles bins w+8k
// (wave-uniform coords). 512-thr blocks double resident waves vs round-5
// (grid 512 = 2 blocks/CU -> 16 waves/CU, occupancy ceiling 25% -> 50%);
// 2 x 50KB LDS = 100KB < 160KB, VGPR 96 -> 20-wave cap, both fit.
// Staged in LDS, then the ROI's contiguous 784-full-line span is written
// with coalesced float4 stores (no partial-line RMW).
// ---------------------------------------------------------------------------
__global__ __launch_bounds__(512) void dcn_pool_roi_kernel(
    const float* __restrict__ xt, const float* __restrict__ rois,
    const float* __restrict__ offs, float* __restrict__ out)
{
    __shared__ __align__(16) float res[CH * 49];   // 50176 B
    const int n = blockIdx.x;

    const float* r = rois + n * 5;
    const int   b  = (int)r[0];
    const float x1 = r[1] * SCALE - 0.5f;
    const float y1 = r[2] * SCALE - 0.5f;
    const float rw = fmaxf(r[3] * SCALE - 0.5f - x1, 1.0f);
    const float rh = fmaxf(r[4] * SCALE - 0.5f - y1, 1.0f);
    const float bw = rw * (1.0f / 7.0f);
    const float bh = rh * (1.0f / 7.0f);

    const int lane = threadIdx.x & 63;
    const int wv   = threadIdx.x >> 6;           // 0..7; bin wave-uniform
    const float* base = xt + ((size_t)b << 22) + 4 * lane;

    for (int bin = wv; bin < 49; bin += 8) {
        const int ph = bin / 7, pw = bin - ph * 7;
        const float offx = GAMMA * rw * offs[n * 98 + bin];
        const float offy = GAMMA * rh * offs[n * 98 + 49 + bin];
        const float xb = x1 + pw * bw + offx;
        const float yb = y1 + ph * bh + offy;

        float4 acc = make_float4(0.0f, 0.0f, 0.0f, 0.0f);
        #pragma unroll
        for (int s = 0; s < 16; ++s) {
            const int   iy = s >> 2, ix = s & 3;
            const float ys = yb + ((float)iy + 0.5f) * 0.25f * bh;
            const float xs = xb + ((float)ix + 0.5f) * 0.25f * bw;
            const bool  valid = (ys > -1.0f) & (ys < 128.0f) &
                                (xs > -1.0f) & (xs < 128.0f);
            const float yc = fminf(fmaxf(ys, 0.0f), 127.0f);
            const float xc = fminf(fmaxf(xs, 0.0f), 127.0f);
            const int   y0 = (int)yc;            // yc >= 0 -> trunc == floor
            const int   x0 = (int)xc;
            const float ly = yc - (float)y0, lx = xc - (float)x0;
            const float hy = 1.0f - ly,      hx = 1.0f - lx;
            const int   y1i = min(y0 + 1, 127), x1i = min(x0 + 1, 127);
            const float wvs = valid ? (1.0f / 16.0f) : 0.0f;   // fold valid + mean
            const float w00 = wvs * hy * hx, w01 = wvs * hy * lx;
            const float w10 = wvs * ly * hx, w11 = wvs * ly * lx;

            const int p00 = (y0 * 128 + x0)  << 8;   // 256 floats per pixel
            const int p01 = (y0 * 128 + x1i) << 8;
            const int p10 = (y1i * 128 + x0) << 8;
            const int p11 = (y1i * 128 + x1i) << 8;
            const float4 v00 = *(const float4*)(base + p00);
            const float4 v01 = *(const float4*)(base + p01);
            const float4 v10 = *(const float4*)(base + p10);
            const float4 v11 = *(const float4*)(base + p11);
            acc.x = fmaf(w00, v00.x, fmaf(w01, v01.x, fmaf(w10, v10.x, fmaf(w11, v11.x, acc.x))));
            acc.y = fmaf(w00, v00.y, fmaf(w01, v01.y, fmaf(w10, v10.y, fmaf(w11, v11.y, acc.y))));
            acc.z = fmaf(w00, v00.z, fmaf(w01, v01.z, fmaf(w10, v10.z, fmaf(w11, v11.z, acc.z))));
            acc.w = fmaf(w00, v00.w, fmaf(w01, v01.w, fmaf(w10, v10.w, fmaf(w11, v11.w, acc.w))));
        }
        // Stage: res[(4l+k)*49 + bin]. 8-way bank conflict (stride 196B),
        // but only ~26 writes per lane total -> negligible (602k cyc measured
        // across the whole dispatch in round 5, ~1% of kernel time).
        float* rb = res + (4 * lane) * 49 + bin;
        rb[0]   = acc.x;
        rb[49]  = acc.y;
        rb[98]  = acc.z;
        rb[147] = acc.w;
    }
    __syncthreads();

    // Coalesced epilogue: 12544 floats = 3136 float4, contiguous global span.
    float*        ob = out + (size_t)n * (CH * 49);
    const float4* rs = (const float4*)res;
    float4*       od = (float4*)ob;
    for (int i = threadIdx.x; i < 3136; i += 512) od[i] = rs[i];
}

// ---------------------------------------------------------------------------
// Fallback (round-1 kernel) if d_ws is too small for the transposed copy.
// ---------------------------------------------------------------------------
struct __attribute__((packed, aligned(4))) f2 { float x, y; };

__global__ __launch_bounds__(256) void dcn_pool_kernel(
    const float* __restrict__ x, const float* __restrict__ rois,
    const float* __restrict__ offs, float* __restrict__ out)
{
    const int bin = blockIdx.x;
    const int n   = bin / 49;
    const int pq  = bin - n * 49;
    const int ph  = pq / 7;
    const int pw  = pq - ph * 7;

    const float* r = rois + n * 5;
    const int   b  = (int)r[0];
    const float x1 = r[1] * SCALE - 0.5f;
    const float y1 = r[2] * SCALE - 0.5f;
    const float x2 = r[3] * SCALE - 0.5f;
    const float y2 = r[4] * SCALE - 0.5f;
    const float rw = fmaxf(x2 - x1, 1.0f);
    const float rh = fmaxf(y2 - y1, 1.0f);
    const float bw = rw * (1.0f / 7.0f);
    const float bh = rh * (1.0f / 7.0f);
    const float offx = GAMMA * rw * offs[n * 98 + pq];
    const float offy = GAMMA * rh * offs[n * 98 + 49 + pq];
    const float xb = x1 + pw * bw + offx;
    const float yb = y1 + ph * bh + offy;

    const int tid    = threadIdx.x;
    const int lane   = tid & 63;
    const int waveId = tid >> 6;
    const int idx    = lane & 31;
    const int s      = idx >> 1;
    const int rrow   = idx & 1;
    const int chHalf = lane >> 5;

    const int   iy = s >> 2, ix = s & 3;
    const float ys = yb + ((float)iy + 0.5f) * 0.25f * bh;
    const float xs = xb + ((float)ix + 0.5f) * 0.25f * bw;
    const bool  valid = (ys > -1.0f) & (ys < 128.0f) & (xs > -1.0f) & (xs < 128.0f);
    const float yc = fminf(fmaxf(ys, 0.0f), 127.0f);
    const float xc = fminf(fmaxf(xs, 0.0f), 127.0f);
    const int   y0 = (int)floorf(yc);
    const int   x0 = (int)floorf(xc);
    const float ly = yc - (float)y0;
    const float lx = xc - (float)x0;
    const int   y1i = min(y0 + 1, 127);
    const int   x0f = min(x0, 126);
    const int   yr  = rrow ? y1i : y0;
    const float wy  = rrow ? ly : (1.0f - ly);

    float wA, wB;
    if (x0 <= 126) { wA = 1.0f - lx; wB = lx; }
    else           { wA = 0.0f;      wB = 1.0f; }
    const float wyv = valid ? wy * (1.0f / 16.0f) : 0.0f;
    wA *= wyv;
    wB *= wyv;

    const int po = yr * 128 + x0f;
    const float* plane0 = x + ((size_t)(b * 256) << 14) + po;

    const int cbase = waveId * 64;
    float resv = 0.0f;
    #pragma unroll
    for (int i = 0; i < 32; ++i) {
        const int c = cbase + 2 * i + chHalf;
        const f2  v = *(const f2*)(plane0 + ((size_t)c << 14));
        float p = wA * v.x + wB * v.y;
        p += __shfl_xor(p, 1);
        p += __shfl_xor(p, 2);
        p += __shfl_xor(p, 4);
        p += __shfl_xor(p, 8);
        p += __shfl_xor(p, 16);
        const float q    = __shfl_xor(p, 32);
        const float mine = ((lane & 1) == chHalf) ? p : q;
        if ((lane >> 1) == i) resv = mine;
    }
    out[((size_t)(n * 256 + cbase + lane)) * 49 + pq] = resv;
}

extern "C" void kernel_launch(void* const* d_in, const int* in_sizes, int n_in,
                              void* d_out, int out_size, void* d_ws, size_t ws_size,
                              hipStream_t stream) {
    const float* x    = (const float*)d_in[0];
    const float* rois = (const float*)d_in[1];
    const float* offs = (const float*)d_in[2];
    float*       out  = (float*)d_out;

    if (ws_size >= XT_BYTES) {
        float* xt = (float*)d_ws;
        transpose_kernel<<<4096, 256, 0, stream>>>(x, xt);
        dcn_pool_roi_kernel<<<NROIS, 512, 0, stream>>>(xt, rois, offs, out);
    } else {
        dcn_pool_kernel<<<NROIS * 49, 256, 0, stream>>>(x, rois, offs, out);
    }
}

// Round 7
// 135.977 us; speedup vs baseline: 1.4006x; 1.4006x over previous
//
#include <hip/hip_runtime.h>

#define NROIS 512
#define CH    256
#define HH    128
#define WW    128
#define SCALE 0.0625f
#define GAMMA 0.1f

// Transposed copy of x: (B,C,H,W) -> (B,H,W,C). 4*128*128*256 floats = 64 MiB.
#define XT_BYTES ((size_t)4 * 128 * 128 * 256 * 4)

// ---------------------------------------------------------------------------
// Kernel 1: tiled transpose per batch: 256 (C) x 16384 (HW) -> 16384 x 256.
// float4 both phases; LDS conflicts are 2-way max (free on gfx950).
// ---------------------------------------------------------------------------
__global__ __launch_bounds__(256) void transpose_kernel(
    const float* __restrict__ x, float* __restrict__ xt)
{
    __shared__ float tile[64][65];           // [c][p], +1 pad
    const int bid = blockIdx.x;              // 256 p-tiles * 4 c-tiles * 4 batches
    const int pt  = bid & 255;
    const int ct  = (bid >> 8) & 3;
    const int b   = bid >> 10;
    const int p0  = pt * 64, c0 = ct * 64;
    const size_t boff = (size_t)b * (256 * 16384);
    const int a = threadIdx.x & 15;          // float4 slot
    const int r = threadIdx.x >> 4;          // 0..15

    #pragma unroll
    for (int i = 0; i < 4; ++i) {            // coalesced float4 reads along HW
        const int cr = r + 16 * i;
        const float4 v = *(const float4*)(x + boff + (size_t)(c0 + cr) * 16384 + p0 + 4 * a);
        tile[cr][4 * a + 0] = v.x;
        tile[cr][4 * a + 1] = v.y;
        tile[cr][4 * a + 2] = v.z;
        tile[cr][4 * a + 3] = v.w;
    }
    __syncthreads();
    #pragma unroll
    for (int i = 0; i < 4; ++i) {            // coalesced float4 writes along C
        const int pr = r + 16 * i;
        float4 v;
        v.x = tile[4 * a + 0][pr];
        v.y = tile[4 * a + 1][pr];
        v.z = tile[4 * a + 2][pr];
        v.w = tile[4 * a + 3][pr];
        *(float4*)(xt + boff + (size_t)(p0 + pr) * 256 + c0 + 4 * a) = v;
    }
}

// ---------------------------------------------------------------------------
// Kernel 2: ONE BLOCK (256 thr) PER ROI, factorized rank-1 bin stencil.
// Bilinear weights separate per axis: sum over the 4x4 sample grid of
// wyvec(iy) (x) wxvec(ix) = (SUM wyvec) (x) (SUM wxvec), so each bin is a
// 4x4 pixel box with weights wy[dy]*wx[dx]. 16 pixel loads/bin instead of
// 64 tap loads (round-6 showed the kernel is bound by the per-CU load
// pipe / per-XCD L2, not waves: 2x occupancy gave 0%). Samples span
// 0.75*bh <= 1.72 px -> dy in {0,1,2}, dy+1 <= 3: 4x4 box always enough.
// Edge clamp: load rows/cols clamped to 127; duplicate cells hit the same
// pixel so the summed weight is exact. valid & mean/16 folded per axis.
// ---------------------------------------------------------------------------
__global__ __launch_bounds__(256) void dcn_pool_roi_kernel(
    const float* __restrict__ xt, const float* __restrict__ rois,
    const float* __restrict__ offs, float* __restrict__ out)
{
    __shared__ __align__(16) float res[CH * 49];   // 50176 B
    const int n = blockIdx.x;

    const float* r = rois + n * 5;
    const int   b  = (int)r[0];
    const float x1 = r[1] * SCALE - 0.5f;
    const float y1 = r[2] * SCALE - 0.5f;
    const float rw = fmaxf(r[3] * SCALE - 0.5f - x1, 1.0f);
    const float rh = fmaxf(r[4] * SCALE - 0.5f - y1, 1.0f);
    const float bw = rw * (1.0f / 7.0f);
    const float bh = rh * (1.0f / 7.0f);

    const int lane = threadIdx.x & 63;
    const int wv   = threadIdx.x >> 6;           // 0..3; bin wave-uniform
    const float* base = xt + ((size_t)b << 22) + 4 * lane;

    for (int bin = wv; bin < 49; bin += 4) {
        const int ph = bin / 7, pw = bin - ph * 7;
        const float offx = GAMMA * rw * offs[n * 98 + bin];
        const float offy = GAMMA * rh * offs[n * 98 + 49 + bin];
        const float xb = x1 + pw * bw + offx;
        const float yb = y1 + ph * bh + offy;
        const float qy = 0.25f * bh, qx = 0.25f * bw;

        // ---- factorized axis weights (wave-uniform math) ----
        float wy0 = 0.f, wy1 = 0.f, wy2 = 0.f, wy3 = 0.f;
        const int ymin = (int)fminf(fmaxf(yb + 0.5f * qy, 0.0f), 127.0f);
        #pragma unroll
        for (int iy = 0; iy < 4; ++iy) {
            const float ys = yb + ((float)iy + 0.5f) * qy;
            const float vy = ((ys > -1.0f) && (ys < 128.0f)) ? 0.25f : 0.0f;
            const float yc = fminf(fmaxf(ys, 0.0f), 127.0f);
            const int   y0 = (int)yc;            // >= ymin, <= ymin+2
            const float ly = yc - (float)y0;
            const float hy = 1.0f - ly;
            const int   dy = y0 - ymin;
            const float ha = hy * vy, la = ly * vy;
            wy0 += (dy == 0) ? ha : 0.0f;
            wy1 += (dy == 0) ? la : ((dy == 1) ? ha : 0.0f);
            wy2 += (dy == 1) ? la : ((dy == 2) ? ha : 0.0f);
            wy3 += (dy == 2) ? la : 0.0f;
        }
        float wx0 = 0.f, wx1 = 0.f, wx2 = 0.f, wx3 = 0.f;
        const int xmin = (int)fminf(fmaxf(xb + 0.5f * qx, 0.0f), 127.0f);
        #pragma unroll
        for (int ix = 0; ix < 4; ++ix) {
            const float xs = xb + ((float)ix + 0.5f) * qx;
            const float vx = ((xs > -1.0f) && (xs < 128.0f)) ? 0.25f : 0.0f;
            const float xc = fminf(fmaxf(xs, 0.0f), 127.0f);
            const int   x0 = (int)xc;
            const float lx = xc - (float)x0;
            const float hx = 1.0f - lx;
            const int   dx = x0 - xmin;
            const float ha = hx * vx, la = lx * vx;
            wx0 += (dx == 0) ? ha : 0.0f;
            wx1 += (dx == 0) ? la : ((dx == 1) ? ha : 0.0f);
            wx2 += (dx == 1) ? la : ((dx == 2) ? ha : 0.0f);
            wx3 += (dx == 2) ? la : 0.0f;
        }
        const float wyv[4] = {wy0, wy1, wy2, wy3};
        const float wxv[4] = {wx0, wx1, wx2, wx3};

        // ---- 4x4 box: 16 coalesced dwordx4 loads, rank-1 weights ----
        float4 acc = make_float4(0.0f, 0.0f, 0.0f, 0.0f);
        #pragma unroll
        for (int dy = 0; dy < 4; ++dy) {
            const int rowoff = (min(ymin + dy, 127) * 128) << 8;
            #pragma unroll
            for (int dx = 0; dx < 4; ++dx) {
                const float w = wyv[dy] * wxv[dx];
                const int   off = rowoff + (min(xmin + dx, 127) << 8);
                const float4 v = *(const float4*)(base + off);
                acc.x = fmaf(w, v.x, acc.x);
                acc.y = fmaf(w, v.y, acc.y);
                acc.z = fmaf(w, v.z, acc.z);
                acc.w = fmaf(w, v.w, acc.w);
            }
        }

        // Stage: res[(4l+k)*49 + bin]; bank conflicts measured negligible.
        float* rb = res + (4 * lane) * 49 + bin;
        rb[0]   = acc.x;
        rb[49]  = acc.y;
        rb[98]  = acc.z;
        rb[147] = acc.w;
    }
    __syncthreads();

    // Coalesced epilogue: 12544 floats = 3136 float4, contiguous full-line
    // span owned entirely by this block (no partial-line RMW).
    float*        ob = out + (size_t)n * (CH * 49);
    const float4* rs = (const float4*)res;
    float4*       od = (float4*)ob;
    for (int i = threadIdx.x; i < 3136; i += 256) od[i] = rs[i];
}

// ---------------------------------------------------------------------------
// Fallback (round-1 kernel) if d_ws is too small for the transposed copy.
// ---------------------------------------------------------------------------
struct __attribute__((packed, aligned(4))) f2 { float x, y; };

__global__ __launch_bounds__(256) void dcn_pool_kernel(
    const float* __restrict__ x, const float* __restrict__ rois,
    const float* __restrict__ offs, float* __restrict__ out)
{
    const int bin = blockIdx.x;
    const int n   = bin / 49;
    const int pq  = bin - n * 49;
    const int ph  = pq / 7;
    const int pw  = pq - ph * 7;

    const float* r = rois + n * 5;
    const int   b  = (int)r[0];
    const float x1 = r[1] * SCALE - 0.5f;
    const float y1 = r[2] * SCALE - 0.5f;
    const float x2 = r[3] * SCALE - 0.5f;
    const float y2 = r[4] * SCALE - 0.5f;
    const float rw = fmaxf(x2 - x1, 1.0f);
    const float rh = fmaxf(y2 - y1, 1.0f);
    const float bw = rw * (1.0f / 7.0f);
    const float bh = rh * (1.0f / 7.0f);
    const float offx = GAMMA * rw * offs[n * 98 + pq];
    const float offy = GAMMA * rh * offs[n * 98 + 49 + pq];
    const float xb = x1 + pw * bw + offx;
    const float yb = y1 + ph * bh + offy;

    const int tid    = threadIdx.x;
    const int lane   = tid & 63;
    const int waveId = tid >> 6;
    const int idx    = lane & 31;
    const int s      = idx >> 1;
    const int rrow   = idx & 1;
    const int chHalf = lane >> 5;

    const int   iy = s >> 2, ix = s & 3;
    const float ys = yb + ((float)iy + 0.5f) * 0.25f * bh;
    const float xs = xb + ((float)ix + 0.5f) * 0.25f * bw;
    const bool  valid = (ys > -1.0f) & (ys < 128.0f) & (xs > -1.0f) & (xs < 128.0f);
    const float yc = fminf(fmaxf(ys, 0.0f), 127.0f);
    const float xc = fminf(fmaxf(xs, 0.0f), 127.0f);
    const int   y0 = (int)floorf(yc);
    const int   x0 = (int)floorf(xc);
    const float ly = yc - (float)y0;
    const float lx = xc - (float)x0;
    const int   y1i = min(y0 + 1, 127);
    const int   x0f = min(x0, 126);
    const int   yr  = rrow ? y1i : y0;
    const float wy  = rrow ? ly : (1.0f - ly);

    float wA, wB;
    if (x0 <= 126) { wA = 1.0f - lx; wB = lx; }
    else           { wA = 0.0f;      wB = 1.0f; }
    const float wyv = valid ? wy * (1.0f / 16.0f) : 0.0f;
    wA *= wyv;
    wB *= wyv;

    const int po = yr * 128 + x0f;
    const float* plane0 = x + ((size_t)(b * 256) << 14) + po;

    const int cbase = waveId * 64;
    float resv = 0.0f;
    #pragma unroll
    for (int i = 0; i < 32; ++i) {
        const int c = cbase + 2 * i + chHalf;
        const f2  v = *(const f2*)(plane0 + ((size_t)c << 14));
        float p = wA * v.x + wB * v.y;
        p += __shfl_xor(p, 1);
        p += __shfl_xor(p, 2);
        p += __shfl_xor(p, 4);
        p += __shfl_xor(p, 8);
        p += __shfl_xor(p, 16);
        const float q    = __shfl_xor(p, 32);
        const float mine = ((lane & 1) == chHalf) ? p : q;
        if ((lane >> 1) == i) resv = mine;
    }
    out[((size_t)(n * 256 + cbase + lane)) * 49 + pq] = resv;
}

extern "C" void kernel_launch(void* const* d_in, const int* in_sizes, int n_in,
                              void* d_out, int out_size, void* d_ws, size_t ws_size,
                              hipStream_t stream) {
    const float* x    = (const float*)d_in[0];
    const float* rois = (const float*)d_in[1];
    const float* offs = (const float*)d_in[2];
    float*       out  = (float*)d_out;

    if (ws_size >= XT_BYTES) {
        float* xt = (float*)d_ws;
        transpose_kernel<<<4096, 256, 0, stream>>>(x, xt);
        dcn_pool_roi_kernel<<<NROIS, 256, 0, stream>>>(xt, rois, offs, out);
    } else {
        dcn_pool_kernel<<<NROIS * 49, 256, 0, stream>>>(x, rois, offs, out);
    }
}